// Round 1
// baseline (876.109 us; speedup 1.0000x reference)
//
#include <hip/hip_runtime.h>

// ---------------- workspace layout (float indices) ----------------
#define WS_W1     0      // 768: Weff1[(p*3+l)*128+i]
#define WS_W2     768    // 768: Weff2
#define WS_C1     1536   // scalar bias for x1[p=0,lm=0]
#define WS_C2     1537
#define WS_CG112  1540   // 81: cg112[(a*3+b)*9+l]
#define WS_CSTART 1624   // 10 ints (c-sorted prefix)
#define WS_CGD    1640   // 729: dense CG[a*81+b*9+c]
#define WS_ABC    2372   // nnz ints: a | b<<4
#define WS_COEF   3104   // nnz floats: CG*wpath
#define WS_TOTAL  3840

__device__ __forceinline__ int d_iabs(int x){ return x < 0 ? -x : x; }
__device__ __forceinline__ int d_lof(int a){ return a == 0 ? 0 : (a < 4 ? 1 : 2); }

__device__ __forceinline__ double dfact(int n){
  double r = 1.0;
  for (int i = 2; i <= n; ++i) r *= (double)i;
  return r;
}

// Complex-basis Clebsch-Gordan (Racah), exact port of the Python
__device__ double dcg_complex(int j1,int m1,int j2,int m2,int j3,int m3){
  if (m3 != m1 + m2 || j3 < d_iabs(j1-j2) || j3 > j1+j2) return 0.0;
  double pref = sqrt((double)(2*j3+1) * dfact(j1+j2-j3) * dfact(j1-j2+j3)
                     * dfact(-j1+j2+j3) / dfact(j1+j2+j3+1));
  pref *= sqrt(dfact(j1+m1)*dfact(j1-m1)*dfact(j2+m2)*dfact(j2-m2)
               *dfact(j3+m3)*dfact(j3-m3));
  double s = 0.0;
  for (int k = 0; k <= j1+j2-j3; ++k){
    int t1 = j1+j2-j3-k, t2 = j1-m1-k, t3 = j2+m2-k, t4 = j3-j2+m1+k, t5 = j3-j1-m2+k;
    if (t1 < 0 || t2 < 0 || t3 < 0 || t4 < 0 || t5 < 0) continue;
    double d = dfact(k)*dfact(t1)*dfact(t2)*dfact(t3)*dfact(t4)*dfact(t5);
    s += ((k & 1) ? -1.0 : 1.0) / d;
  }
  return pref * s;
}

// U_l[row rr, col q] of the complex->real change of basis (rows m=-l..l)
__device__ __forceinline__ void d_uent(int l, int rr, int q, double& re, double& im){
  re = 0.0; im = 0.0;
  const double inv = 0.70710678118654752440;
  int mu = rr - l;
  if (mu == 0){ if (q == l) re = 1.0; return; }
  int m = mu > 0 ? mu : -mu;
  double sgn = (m & 1) ? -1.0 : 1.0;
  if (mu > 0){
    if (q == l - m)      re = inv;
    else if (q == l + m) re = sgn * inv;
  } else {
    if (q == l - m)      im = inv;
    else if (q == l + m) im = -sgn * inv;
  }
}

// Real-basis CG[a][b][c] (e3x lm ordering), a,b,c in [0,9)
__device__ double d_cg_entry(int a, int b, int c){
  int l1 = d_lof(a), l2 = d_lof(b), l3 = d_lof(c);
  if (l3 < d_iabs(l1-l2) || l3 > l1+l2) return 0.0;
  int r1 = a - l1*l1, r2 = b - l2*l2, r3 = c - l3*l3;
  int am1 = d_iabs(r1 - l1), am2 = d_iabs(r2 - l2), am3 = d_iabs(r3 - l3);
  double tre = 0.0, tim = 0.0;
  for (int s1v = 0; s1v < (am1 ? 2 : 1); ++s1v){
    int q1 = l1 + (s1v ? am1 : -am1);
    double u1r, u1i; d_uent(l1, r1, q1, u1r, u1i);
    for (int s2v = 0; s2v < (am2 ? 2 : 1); ++s2v){
      int q2 = l2 + (s2v ? am2 : -am2);
      double u2r, u2i; d_uent(l2, r2, q2, u2r, u2i);
      for (int s3v = 0; s3v < (am3 ? 2 : 1); ++s3v){
        int q3 = l3 + (s3v ? am3 : -am3);
        double u3r, u3i; d_uent(l3, r3, q3, u3r, u3i);
        double C = dcg_complex(l1, q1-l1, l2, q2-l2, l3, q3-l3);
        if (C == 0.0) continue;
        // w = conj(u1)*conj(u2)*u3
        double ar = u1r, ai = -u1i;
        double br = u2r, bi = -u2i;
        double cr = ar*br - ai*bi, ci = ar*bi + ai*br;
        double wr = cr*u3r - ci*u3i, wi = cr*u3i + ci*u3r;
        tre += wr * C; tim += wi * C;
      }
    }
  }
  return ((l1+l2+l3) & 1) ? tim : tre;
}

// K1: Weff1/Weff2 (blocks 0-2), dense CG + bias scalars (block 3)
__global__ __launch_bounds__(256) void k_precompute(
    const float* __restrict__ W3, const float* __restrict__ b3,
    const float* __restrict__ Wt1, const float* __restrict__ bt1,
    const float* __restrict__ Wt2, const float* __restrict__ bt2,
    float* __restrict__ ws){
  if (blockIdx.x < 3){
    int e = blockIdx.x*256 + threadIdx.x;          // 0..767 = (p*3+l)*128 + i
    int pl = e >> 7;
    const float4* w3row = (const float4*)(W3 + (size_t)e*128);
    const float4* u1 = (const float4*)(Wt1 + pl*128);
    const float4* u2 = (const float4*)(Wt2 + pl*128);
    float a1 = 0.f, a2 = 0.f;
    #pragma unroll 8
    for (int j = 0; j < 32; ++j){
      float4 w = w3row[j], x1 = u1[j], x2 = u2[j];
      a1 += w.x*x1.x + w.y*x1.y + w.z*x1.z + w.w*x1.w;
      a2 += w.x*x2.x + w.y*x2.y + w.z*x2.z + w.w*x2.w;
    }
    ws[WS_W1 + e] = a1;
    ws[WS_W2 + e] = a2;
  } else {
    int t = threadIdx.x;
    for (int idx = t; idx < 729; idx += 256){
      int a = idx / 81, b = (idx / 9) % 9, c = idx % 9;
      ws[WS_CGD + idx] = (float)d_cg_entry(a, b, c);
    }
    if (t == 254){
      float s = bt1[0];
      for (int o = 0; o < 128; ++o) s += b3[o]*Wt1[o];
      ws[WS_C1] = s;
    }
    if (t == 255){
      float s = bt2[0];
      for (int o = 0; o < 128; ++o) s += b3[o]*Wt2[o];
      ws[WS_C2] = s;
    }
  }
}

// K2: c-sorted sparse list of CG, coefficients folded with wpath; cg112 slice
__global__ __launch_bounds__(128) void k_sparse(const float* __restrict__ wpath,
                                                float* __restrict__ ws){
  int t = threadIdx.x;
  if (t < 81){
    int ab = t / 9, l = t % 9, a = ab / 3, b = ab % 3;
    ws[WS_CG112 + t] = ws[WS_CGD + (1+a)*81 + (1+b)*9 + l];
  }
  if (t == 127){
    int* wsI = (int*)ws;
    int nnz = 0;
    for (int c = 0; c < 9; ++c){
      wsI[WS_CSTART + c] = nnz;
      for (int a = 0; a < 9; ++a)
        for (int b = 0; b < 9; ++b){
          float v = ws[WS_CGD + a*81 + b*9 + c];
          if (fabsf(v) > 1e-6f){
            int lof = (d_lof(a)*3 + d_lof(b))*3 + d_lof(c);
            wsI[WS_ABC + nnz] = a | (b << 4);
            ws[WS_COEF + nnz] = v * wpath[lof];
            nnz++;
          }
        }
    }
    wsI[WS_CSTART + 9] = nnz;
  }
}

// One (p,l) block of the fused x1/x2 dot-products. Template params keep all
// register-array indices compile-time constant (no scratch spill).
template<int P, int L>
__device__ __forceinline__ void accum_block(const float* __restrict__ xn,
    const float* lds, int part, float* s1, float* s2){
  float4 w1v[8], w2v[8];
  const int wb = (P*3 + L)*128 + part*4;
  #pragma unroll
  for (int j = 0; j < 8; ++j){
    w1v[j] = *(const float4*)&lds[WS_W1 + wb + 16*j];
    w2v[j] = *(const float4*)&lds[WS_W2 + wb + 16*j];
  }
  #pragma unroll
  for (int mi = 0; mi < 2*L + 1; ++mi){
    const int r = P*9 + L*L + mi;
    const float* xr = xn + (P*9 + L*L + mi)*128;
    #pragma unroll
    for (int j = 0; j < 8; ++j){
      float4 xv = *(const float4*)&xr[16*j];
      s1[r] += xv.x*w1v[j].x + xv.y*w1v[j].y + xv.z*w1v[j].z + xv.w*w1v[j].w;
      s2[r] += xv.x*w2v[j].x + xv.y*w2v[j].y + xv.z*w2v[j].z + xv.w*w2v[j].w;
    }
  }
}

#define GSTRIDE 41   // 36 values per group, 41 to decorrelate LDS banks

__global__ __launch_bounds__(256) void k_main(
    const float* __restrict__ sf, const float* __restrict__ ws,
    float* __restrict__ out, int N){
  __shared__ __align__(16) float lds[WS_TOTAL + 64*GSTRIDE];
  for (int k = threadIdx.x; k < WS_TOTAL; k += 256) lds[k] = ws[k];
  __syncthreads();

  const int lane = threadIdx.x & 63;
  const int wave = threadIdx.x >> 6;
  const int part = lane & 3;               // 4 lanes cooperate on one n
  const int grpb = threadIdx.x >> 2;       // group id within block (0..63)
  const int n = blockIdx.x*64 + wave*16 + (lane >> 2);

  float s1[18], s2[18];
  #pragma unroll
  for (int r = 0; r < 18; ++r){ s1[r] = 0.f; s2[r] = 0.f; }

  if (n < N){
    const float* xn = sf + (size_t)n * 2304 + part*4;
    accum_block<0,0>(xn, lds, part, s1, s2);
    accum_block<0,1>(xn, lds, part, s1, s2);
    accum_block<0,2>(xn, lds, part, s1, s2);
    accum_block<1,0>(xn, lds, part, s1, s2);
    accum_block<1,1>(xn, lds, part, s1, s2);
    accum_block<1,2>(xn, lds, part, s1, s2);
  }

  // reduce the 4 partial lanes (2 butterfly steps) -> all 4 lanes hold sums
  #pragma unroll
  for (int r = 0; r < 18; ++r){
    s1[r] += __shfl_xor(s1[r], 1); s1[r] += __shfl_xor(s1[r], 2);
    s2[r] += __shfl_xor(s2[r], 1); s2[r] += __shfl_xor(s2[r], 2);
  }
  s1[0] += lds[WS_C1];     // bias lands only on (p=0, lm=0)
  s2[0] += lds[WS_C2];

  // park per-n sums in LDS so the sparse contraction can index dynamically
  float* sg = &lds[WS_TOTAL + grpb*GSTRIDE];
  if (part == 0){
    #pragma unroll
    for (int r = 0; r < 18; ++r) sg[r] = s1[r];        // x1: [p0 0..8][p1 9..17]
  } else if (part == 1){
    #pragma unroll
    for (int r = 0; r < 18; ++r) sg[18 + r] = s2[r];   // x2 at +18
  }
  __syncthreads();

  const int* ldsI = (const int*)lds;
  float v[9];
  #pragma unroll
  for (int c = 0; c < 9; ++c){
    float acc = 0.f;
    const int e0 = ldsI[WS_CSTART + c], e1 = ldsI[WS_CSTART + c + 1];
    for (int e = e0 + part; e < e1; e += 4){
      const int pk = ldsI[WS_ABC + e];
      const int a = pk & 15, b = (pk >> 4) & 15;
      const float coef = lds[WS_COEF + e];
      acc += (sg[a]*sg[18 + b] + sg[9 + a]*sg[27 + b]) * coef;
    }
    acc += __shfl_xor(acc, 1);
    acc += __shfl_xor(acc, 2);
    v[c] = acc;
  }

  if (n < N){
    #pragma unroll
    for (int k = 0; k < 3; ++k){
      const int j = part + 4*k;
      if (j < 9){
        float o = 0.f;
        #pragma unroll
        for (int l = 0; l < 9; ++l) o += v[l]*lds[WS_CG112 + j*9 + l];
        out[(size_t)n*9 + j] = o;
      }
    }
  }
}

extern "C" void kernel_launch(void* const* d_in, const int* in_sizes, int n_in,
                              void* d_out, int out_size, void* d_ws, size_t ws_size,
                              hipStream_t stream) {
  const float* sf    = (const float*)d_in[0];
  const float* W3    = (const float*)d_in[1];
  const float* b3    = (const float*)d_in[2];
  const float* Wt1   = (const float*)d_in[3];
  const float* bt1   = (const float*)d_in[4];
  const float* Wt2   = (const float*)d_in[5];
  const float* bt2   = (const float*)d_in[6];
  const float* wpath = (const float*)d_in[7];
  float* out = (float*)d_out;
  float* ws  = (float*)d_ws;

  const int N = in_sizes[0] / 2304;   // (N, 2, 9, 128)

  hipLaunchKernelGGL(k_precompute, dim3(4), dim3(256), 0, stream,
                     W3, b3, Wt1, bt1, Wt2, bt2, ws);
  hipLaunchKernelGGL(k_sparse, dim3(1), dim3(128), 0, stream, wpath, ws);
  const int nblocks = (N + 63) / 64;
  hipLaunchKernelGGL(k_main, dim3(nblocks), dim3(256), 0, stream, sf, ws, out, N);
}

// Round 3
// 817.230 us; speedup vs baseline: 1.0720x; 1.0720x over previous
//
#include <hip/hip_runtime.h>

// ---------------- workspace layout (float indices) ----------------
#define WS_W1     0      // 768: Weff1[(p*3+l)*128+i]
#define WS_W2     768    // 768: Weff2
#define WS_C1     1536   // scalar bias for x1[p=0,lm=0]
#define WS_C2     1537
#define WS_CG112  1540   // 81: cg112[(a*3+b)*9+l]
#define WS_CSTART 1624   // 10 ints (c-sorted prefix)
#define WS_ABC    2372   // nnz ints: a | b<<4
#define WS_COEF   3104   // nnz floats: CG*wpath
#define WS_TOTAL  3840

__device__ __forceinline__ int d_iabs(int x){ return x < 0 ? -x : x; }
__device__ __forceinline__ int d_lof(int a){ return a == 0 ? 0 : (a < 4 ? 1 : 2); }

__device__ __forceinline__ double dfact(int n){
  double r = 1.0;
  for (int i = 2; i <= n; ++i) r *= (double)i;
  return r;
}

// Complex-basis Clebsch-Gordan (Racah), exact port of the Python
__device__ double dcg_complex(int j1,int m1,int j2,int m2,int j3,int m3){
  if (m3 != m1 + m2 || j3 < d_iabs(j1-j2) || j3 > j1+j2) return 0.0;
  double pref = sqrt((double)(2*j3+1) * dfact(j1+j2-j3) * dfact(j1-j2+j3)
                     * dfact(-j1+j2+j3) / dfact(j1+j2+j3+1));
  pref *= sqrt(dfact(j1+m1)*dfact(j1-m1)*dfact(j2+m2)*dfact(j2-m2)
               *dfact(j3+m3)*dfact(j3-m3));
  double s = 0.0;
  for (int k = 0; k <= j1+j2-j3; ++k){
    int t1 = j1+j2-j3-k, t2 = j1-m1-k, t3 = j2+m2-k, t4 = j3-j2+m1+k, t5 = j3-j1-m2+k;
    if (t1 < 0 || t2 < 0 || t3 < 0 || t4 < 0 || t5 < 0) continue;
    double d = dfact(k)*dfact(t1)*dfact(t2)*dfact(t3)*dfact(t4)*dfact(t5);
    s += ((k & 1) ? -1.0 : 1.0) / d;
  }
  return pref * s;
}

// U_l[row rr, col q] of the complex->real change of basis (rows m=-l..l)
__device__ __forceinline__ void d_uent(int l, int rr, int q, double& re, double& im){
  re = 0.0; im = 0.0;
  const double inv = 0.70710678118654752440;
  int mu = rr - l;
  if (mu == 0){ if (q == l) re = 1.0; return; }
  int m = mu > 0 ? mu : -mu;
  double sgn = (m & 1) ? -1.0 : 1.0;
  if (mu > 0){
    if (q == l - m)      re = inv;
    else if (q == l + m) re = sgn * inv;
  } else {
    if (q == l - m)      im = inv;
    else if (q == l + m) im = -sgn * inv;
  }
}

// Real-basis CG[a][b][c] (e3x lm ordering), a,b,c in [0,9)
__device__ double d_cg_entry(int a, int b, int c){
  int l1 = d_lof(a), l2 = d_lof(b), l3 = d_lof(c);
  if (l3 < d_iabs(l1-l2) || l3 > l1+l2) return 0.0;
  int r1 = a - l1*l1, r2 = b - l2*l2, r3 = c - l3*l3;
  int am1 = d_iabs(r1 - l1), am2 = d_iabs(r2 - l2), am3 = d_iabs(r3 - l3);
  double tre = 0.0, tim = 0.0;
  for (int s1v = 0; s1v < (am1 ? 2 : 1); ++s1v){
    int q1 = l1 + (s1v ? am1 : -am1);
    double u1r, u1i; d_uent(l1, r1, q1, u1r, u1i);
    for (int s2v = 0; s2v < (am2 ? 2 : 1); ++s2v){
      int q2 = l2 + (s2v ? am2 : -am2);
      double u2r, u2i; d_uent(l2, r2, q2, u2r, u2i);
      for (int s3v = 0; s3v < (am3 ? 2 : 1); ++s3v){
        int q3 = l3 + (s3v ? am3 : -am3);
        double u3r, u3i; d_uent(l3, r3, q3, u3r, u3i);
        double C = dcg_complex(l1, q1-l1, l2, q2-l2, l3, q3-l3);
        if (C == 0.0) continue;
        // w = conj(u1)*conj(u2)*u3
        double ar = u1r, ai = -u1i;
        double br = u2r, bi = -u2i;
        double cr = ar*br - ai*bi, ci = ar*bi + ai*br;
        double wr = cr*u3r - ci*u3i, wi = cr*u3i + ci*u3r;
        tre += wr * C; tim += wi * C;
      }
    }
  }
  return ((l1+l2+l3) & 1) ? tim : tre;
}

// Single prep kernel, fully parallel (no serial global-latency chains).
// Blocks 0-2: Weff1/Weff2.  Block 3: biases + dense CG in LDS + parallel
// sparse compaction + cg112 slice.
__global__ __launch_bounds__(256) void k_prep(
    const float* __restrict__ W3, const float* __restrict__ b3,
    const float* __restrict__ Wt1, const float* __restrict__ bt1,
    const float* __restrict__ Wt2, const float* __restrict__ bt2,
    const float* __restrict__ wpath, float* __restrict__ ws){
  if (blockIdx.x < 3){
    int e = blockIdx.x*256 + threadIdx.x;          // 0..767 = (p*3+l)*128 + i
    int pl = e >> 7;
    const float4* w3row = (const float4*)(W3 + (size_t)e*128);
    const float4* u1 = (const float4*)(Wt1 + pl*128);
    const float4* u2 = (const float4*)(Wt2 + pl*128);
    float a1 = 0.f, a2 = 0.f;
    #pragma unroll 8
    for (int j = 0; j < 32; ++j){
      float4 w = w3row[j], x1 = u1[j], x2 = u2[j];
      a1 += w.x*x1.x + w.y*x1.y + w.z*x1.z + w.w*x1.w;
      a2 += w.x*x2.x + w.y*x2.y + w.z*x2.z + w.w*x2.w;
    }
    ws[WS_W1 + e] = a1;
    ws[WS_W2 + e] = a2;
    return;
  }

  __shared__ float cgl[729];     // dense CG[a*81+b*9+c]
  __shared__ int   pflag[729];   // nonzero flags in (c,a,b) item order
  __shared__ int   cst[10];      // per-c prefix
  const int t = threadIdx.x;

  // dense CG (parallel, doubles)
  for (int idx = t; idx < 729; idx += 256){
    int a = idx / 81, b = (idx / 9) % 9, c = idx % 9;
    cgl[idx] = (float)d_cg_entry(a, b, c);
  }

  // bias scalars: wave 0 -> C1, wave 1 -> C2 (butterfly reduce 128 values)
  if (t < 128){
    const float* Wt = (t < 64) ? Wt1 : Wt2;
    int lane = t & 63;
    float s = b3[lane]*Wt[lane] + b3[lane+64]*Wt[lane+64];
    #pragma unroll
    for (int off = 1; off < 64; off <<= 1) s += __shfl_xor(s, off);
    if (lane == 0) ws[(t < 64) ? WS_C1 : WS_C2] = s + ((t < 64) ? bt1[0] : bt2[0]);
  }
  __syncthreads();

  // cg112 slice: CG[1:4,1:4,:]
  if (t < 81){
    int ab = t / 9, l = t % 9, a = ab / 3, b = ab % 3;
    ws[WS_CG112 + t] = cgl[(1+a)*81 + (1+b)*9 + l];
  }

  // nonzero flags in output (c,a,b) ordering
  for (int i = t; i < 729; i += 256){
    int c = i / 81, a = (i / 9) % 9, b = i % 9;
    pflag[i] = (fabsf(cgl[a*81 + b*9 + c]) > 1e-6f) ? 1 : 0;
  }
  __syncthreads();

  // per-c counts (9 threads x 81 LDS reads)
  if (t < 9){
    int cnt = 0;
    for (int j = 0; j < 81; ++j) cnt += pflag[t*81 + j];
    cst[t + 1] = cnt;
  }
  __syncthreads();
  if (t == 0){
    cst[0] = 0;
    for (int c = 0; c < 9; ++c) cst[c+1] += cst[c];
    int* wsI = (int*)ws;
    for (int c = 0; c <= 9; ++c) wsI[WS_CSTART + c] = cst[c];
  }
  __syncthreads();

  // each nonzero item computes its rank within its c-group and writes its slot
  int* wsI = (int*)ws;
  for (int i = t; i < 729; i += 256){
    if (!pflag[i]) continue;
    int c = i / 81, a = (i / 9) % 9, b = i % 9;
    int base = c*81, off = i - base;           // a*9+b
    int rank = 0;
    for (int j = 0; j < off; ++j) rank += pflag[base + j];
    int pos = cst[c] + rank;
    int lof = (d_lof(a)*3 + d_lof(b))*3 + d_lof(c);
    wsI[WS_ABC + pos] = a | (b << 4);
    ws[WS_COEF + pos] = cgl[a*81 + b*9 + c] * wpath[lof];
  }
}

// One (p,l) block of the fused x1/x2 dot-products. Template params keep all
// register-array indices compile-time constant (no scratch spill).
template<int P, int L>
__device__ __forceinline__ void accum_block(const float* __restrict__ xn,
    const float* lds, int part, float* s1, float* s2){
  float4 w1v[8], w2v[8];
  const int wb = (P*3 + L)*128 + part*4;
  #pragma unroll
  for (int j = 0; j < 8; ++j){
    w1v[j] = *(const float4*)&lds[WS_W1 + wb + 16*j];
    w2v[j] = *(const float4*)&lds[WS_W2 + wb + 16*j];
  }
  #pragma unroll
  for (int mi = 0; mi < 2*L + 1; ++mi){
    const int r = P*9 + L*L + mi;
    const float* xr = xn + (P*9 + L*L + mi)*128;
    #pragma unroll
    for (int j = 0; j < 8; ++j){
      float4 xv = *(const float4*)&xr[16*j];
      s1[r] += xv.x*w1v[j].x + xv.y*w1v[j].y + xv.z*w1v[j].z + xv.w*w1v[j].w;
      s2[r] += xv.x*w2v[j].x + xv.y*w2v[j].y + xv.z*w2v[j].z + xv.w*w2v[j].w;
    }
  }
}

#define GSTRIDE 41   // 36 values per group, 41 to decorrelate LDS banks

__global__ __launch_bounds__(256) void k_main(
    const float* __restrict__ sf, const float* __restrict__ ws,
    float* __restrict__ out, int N){
  __shared__ __align__(16) float lds[WS_TOTAL + 64*GSTRIDE];
  for (int k = threadIdx.x; k < WS_TOTAL; k += 256) lds[k] = ws[k];
  __syncthreads();

  const int lane = threadIdx.x & 63;
  const int wave = threadIdx.x >> 6;
  const int part = lane & 3;               // 4 lanes cooperate on one n
  const int grpb = threadIdx.x >> 2;       // group id within block (0..63)
  const int n = blockIdx.x*64 + wave*16 + (lane >> 2);

  float s1[18], s2[18];
  #pragma unroll
  for (int r = 0; r < 18; ++r){ s1[r] = 0.f; s2[r] = 0.f; }

  if (n < N){
    const float* xn = sf + (size_t)n * 2304 + part*4;
    accum_block<0,0>(xn, lds, part, s1, s2);
    accum_block<0,1>(xn, lds, part, s1, s2);
    accum_block<0,2>(xn, lds, part, s1, s2);
    accum_block<1,0>(xn, lds, part, s1, s2);
    accum_block<1,1>(xn, lds, part, s1, s2);
    accum_block<1,2>(xn, lds, part, s1, s2);
  }

  // reduce the 4 partial lanes (2 butterfly steps) -> all 4 lanes hold sums
  #pragma unroll
  for (int r = 0; r < 18; ++r){
    s1[r] += __shfl_xor(s1[r], 1); s1[r] += __shfl_xor(s1[r], 2);
    s2[r] += __shfl_xor(s2[r], 1); s2[r] += __shfl_xor(s2[r], 2);
  }
  s1[0] += lds[WS_C1];     // bias lands only on (p=0, lm=0)
  s2[0] += lds[WS_C2];

  // park per-n sums in LDS so the sparse contraction can index dynamically
  float* sg = &lds[WS_TOTAL + grpb*GSTRIDE];
  if (part == 0){
    #pragma unroll
    for (int r = 0; r < 18; ++r) sg[r] = s1[r];        // x1: [p0 0..8][p1 9..17]
  } else if (part == 1){
    #pragma unroll
    for (int r = 0; r < 18; ++r) sg[18 + r] = s2[r];   // x2 at +18
  }
  __syncthreads();

  const int* ldsI = (const int*)lds;
  float v[9];
  #pragma unroll
  for (int c = 0; c < 9; ++c){
    float acc = 0.f;
    const int e0 = ldsI[WS_CSTART + c], e1 = ldsI[WS_CSTART + c + 1];
    for (int e = e0 + part; e < e1; e += 4){
      const int pk = ldsI[WS_ABC + e];
      const int a = pk & 15, b = (pk >> 4) & 15;
      const float coef = lds[WS_COEF + e];
      acc += (sg[a]*sg[18 + b] + sg[9 + a]*sg[27 + b]) * coef;
    }
    acc += __shfl_xor(acc, 1);
    acc += __shfl_xor(acc, 2);
    v[c] = acc;
  }

  if (n < N){
    #pragma unroll
    for (int k = 0; k < 3; ++k){
      const int j = part + 4*k;
      if (j < 9){
        float o = 0.f;
        #pragma unroll
        for (int l = 0; l < 9; ++l) o += v[l]*lds[WS_CG112 + j*9 + l];
        out[(size_t)n*9 + j] = o;
      }
    }
  }
}

extern "C" void kernel_launch(void* const* d_in, const int* in_sizes, int n_in,
                              void* d_out, int out_size, void* d_ws, size_t ws_size,
                              hipStream_t stream) {
  const float* sf    = (const float*)d_in[0];
  const float* W3    = (const float*)d_in[1];
  const float* b3    = (const float*)d_in[2];
  const float* Wt1   = (const float*)d_in[3];
  const float* bt1   = (const float*)d_in[4];
  const float* Wt2   = (const float*)d_in[5];
  const float* bt2   = (const float*)d_in[6];
  const float* wpath = (const float*)d_in[7];
  float* out = (float*)d_out;
  float* ws  = (float*)d_ws;

  const int N = in_sizes[0] / 2304;   // (N, 2, 9, 128)

  hipLaunchKernelGGL(k_prep, dim3(4), dim3(256), 0, stream,
                     W3, b3, Wt1, bt1, Wt2, bt2, wpath, ws);
  const int nblocks = (N + 63) / 64;
  hipLaunchKernelGGL(k_main, dim3(nblocks), dim3(256), 0, stream, sf, ws, out, N);
}